// Round 6
// baseline (182.450 us; speedup 1.0000x reference)
//
#include <hip/hip_runtime.h>
#include <math.h>

#define N_PTS     131072
#define G_NUMS    30
#define G_SIZE    100
#define PT_STRIDE (N_PTS / G_NUMS)   // 4369
#define TPB       512
#define NWAVES    (TPB / 64)         // 8
#define BINS      4096
#define JB        (BINS / TPB)       // 8 bins per thread
#define SHIFT     20

// chunk-parallel scan
#define NCHUNK    32
#define CHUNK     (N_PTS / NCHUNK)   // 4096 points per chunk
#define CPT       (CHUNK / TPB)      // 8 points per thread
#define SMP_N     2048               // scan-kernel sample (iid: first 2048 pts)
#define SMP_PT    (SMP_N / TPB)      // 4
#define SMP_CUT   16                 // 16th of 2048 ~ quantile 1/128
#define SLAB_CAP  128                // per-(group,chunk) survivor slab

// merge / fallback path
#define SAMPLE_GRPS 1024             // fallback sample: first 4096 pts (AoS)
#define RANK_CUT  32
#define CAP       3072               // max merged survivors held in LDS
#define TIE_CAP   64

__device__ __forceinline__ float dist2f(float px, float py, float pz,
                                        float qx, float qy, float qz) {
    float dx = px - qx, dy = py - qy, dz = pz - qz;
    return fmaf(dx, dx, fmaf(dy, dy, dz * dz));
}

// Find smallest bin T such that cumulative count through T >= rank.
// hist[BINS] populated; wsum[NWAVES], *T shared scratch. 3 internal barriers.
__device__ __forceinline__ unsigned find_bin(unsigned* hist, unsigned* wsum,
                                             unsigned* T, unsigned rank,
                                             int tid, int lane, int wid) {
    unsigned hv[JB], csum = 0;
#pragma unroll
    for (int j = 0; j < JB; j++) { hv[j] = hist[tid * JB + j]; csum += hv[j]; }
    unsigned inc = csum;
#pragma unroll
    for (int off = 1; off < 64; off <<= 1) {
        unsigned n = __shfl_up(inc, off);
        if (lane >= off) inc += n;
    }
    __syncthreads();                  // protect wsum reuse across calls
    if (lane == 63) wsum[wid] = inc;
    __syncthreads();
    unsigned base = 0;
    for (int w = 0; w < wid; w++) base += wsum[w];
    unsigned c = base + inc - csum;   // exclusive prefix before this thread's chunk
#pragma unroll
    for (int j = 0; j < JB; j++) {
        if (c < rank && c + hv[j] >= rank) *T = (unsigned)(tid * JB + j);
        c += hv[j];
    }
    __syncthreads();
    return *T;
}

// =============================== scan kernel ===============================
// One block per (batch, chunk). Reads each point ONCE:
//   stage sample -> regs -> 30 taus (identical across blocks of a batch)
//   stage chunk  -> regs -> filter chunk for all 30 queries -> slabs.
union ScanU {
    float    stage[CHUNK * 3];           // 48 KB (largest member)
    unsigned hist[BINS];                 // 16 KB
    uint2    seg[G_NUMS * SLAB_CAP];     // 30 KB
};

__global__ __launch_bounds__(TPB)
void scan_kernel(const float* __restrict__ pts,
                 unsigned* __restrict__ taus, unsigned* __restrict__ cnts,
                 uint2* __restrict__ slabs, unsigned* __restrict__ syncw,
                 int B) {
    __shared__ ScanU su;
    __shared__ float qb[G_NUMS * 3];
    __shared__ unsigned tau_l[G_NUMS];
    __shared__ unsigned scnt[G_NUMS];
    __shared__ unsigned s_wsum[NWAVES];
    __shared__ unsigned s_T;

    const int b = blockIdx.x % B;        // batch-per-XCD swizzle (L2 locality)
    const int c = blockIdx.x / B;
    const float* __restrict__ P = pts + (size_t)b * (N_PTS * 3);
    const float4* __restrict__ P4 = (const float4*)P;
    const int tid = threadIdx.x;
    const int lane = tid & 63, wid = tid >> 6;

    if (blockIdx.x == 0 && tid == 0) syncw[0] = 0;   // replaces memset dispatch

    // queries (strided centers) + counters
    if (tid < G_NUMS) {
        const float* qp = P + (size_t)tid * PT_STRIDE * 3;
        qb[tid * 3 + 0] = qp[0]; qb[tid * 3 + 1] = qp[1]; qb[tid * 3 + 2] = qp[2];
        scnt[tid] = 0u;
    }

    // ---- stage sample (first SMP_N points, coalesced float4) -> regs ----
    for (int j = tid; j < SMP_N * 3 / 4; j += TPB) ((float4*)su.stage)[j] = P4[j];
    __syncthreads();
    float sp[SMP_PT][3];
#pragma unroll
    for (int k = 0; k < SMP_PT; k++) {
        int p = tid + k * TPB;
        sp[k][0] = su.stage[3 * p + 0];
        sp[k][1] = su.stage[3 * p + 1];
        sp[k][2] = su.stage[3 * p + 2];
    }
    __syncthreads();                     // stage dead -> hist usable

    // ---- per-query tau from sample (coarse histogram, rank SMP_CUT) ----
    for (int g = 0; g < G_NUMS; ++g) {
        for (int j = tid; j < BINS; j += TPB) su.hist[j] = 0u;
        if (tid == 0) s_T = 0u;
        __syncthreads();
        float qx = qb[g * 3 + 0], qy = qb[g * 3 + 1], qz = qb[g * 3 + 2];
#pragma unroll
        for (int k = 0; k < SMP_PT; k++) {
            unsigned d = __float_as_uint(dist2f(sp[k][0], sp[k][1], sp[k][2], qx, qy, qz));
            atomicAdd(&su.hist[d >> SHIFT], 1u);
        }
        __syncthreads();
        unsigned Tc = find_bin(su.hist, s_wsum, &s_T, SMP_CUT, tid, lane, wid);
        if (tid == 0)
            tau_l[g] = (Tc >= BINS - 1) ? 0xFFFFFFFFu : ((Tc + 1) << SHIFT);
    }
    __syncthreads();                     // taus ready; hist dead

    // ---- stage own chunk -> regs ----
    const float4* C4 = P4 + (size_t)c * (CHUNK * 3 / 4);
    for (int j = tid; j < CHUNK * 3 / 4; j += TPB) ((float4*)su.stage)[j] = C4[j];
    __syncthreads();
    float cp[CPT][3];
#pragma unroll
    for (int k = 0; k < CPT; k++) {
        int p = tid + k * TPB;
        cp[k][0] = su.stage[3 * p + 0];
        cp[k][1] = su.stage[3 * p + 1];
        cp[k][2] = su.stage[3 * p + 2];
    }
    __syncthreads();                     // stage dead -> seg usable

    // ---- filter chunk for all 30 queries (pure VALU; pushes rare) ----
    const int ib = c * CHUNK + tid;
    for (int g = 0; g < G_NUMS; ++g) {
        float qx = qb[g * 3 + 0], qy = qb[g * 3 + 1], qz = qb[g * 3 + 2];
        unsigned tau = tau_l[g];
#pragma unroll
        for (int k = 0; k < CPT; k++) {
            unsigned uu = __float_as_uint(dist2f(cp[k][0], cp[k][1], cp[k][2], qx, qy, qz));
            if (uu < tau) {
                unsigned p = atomicAdd(&scnt[g], 1u);
                if (p < SLAB_CAP)
                    su.seg[g * SLAB_CAP + p] = make_uint2(uu, (unsigned)(ib + k * TPB));
            }
        }
    }
    __syncthreads();

    // ---- flush segments to global slabs ----
    for (int e = tid; e < G_NUMS * SLAB_CAP; e += TPB) {
        int g = e / SLAB_CAP, p = e % SLAB_CAP;
        unsigned n = scnt[g]; if (n > SLAB_CAP) n = SLAB_CAP;
        if ((unsigned)p < n)
            slabs[((size_t)(b * G_NUMS + g) * NCHUNK + c) * SLAB_CAP + p] = su.seg[e];
    }
    if (tid < G_NUMS)
        cnts[(size_t)(b * G_NUMS + tid) * NCHUNK + c] = scnt[tid];   // RAW (overflow detect)
    if (c == 0 && tid < G_NUMS)
        taus[b * G_NUMS + tid] = tau_l[tid];
}

// =============================== merge kernel ==============================
struct KSmem {
    union {
        unsigned hist[BINS];         // 16 KB
        struct {                     // finalize overlay (last block only)
            float gm[256][3];
            float dir[256][3];
            float pe[NWAVES];
            float ps[NWAVES];
        } fin;
    };
    unsigned wsum[NWAVES];
    unsigned T;
    int ns, nd, nt;
    unsigned u[CAP];
    int idx[CAP];
    float px[CAP], py[CAP], pz[CAP];
    int sel[G_SIZE];                 // positions into survivor arrays
    unsigned tu[TIE_CAP];
    int ti[TIE_CAP];                 // positions
    float acc[3], cov[6], q[3];
    unsigned tau0, maxu, r1;
    float delta2;
};

// AoS full scan (fallback): fills sm.u/idx/px/py/pz/ns (and tau0 if save_tau).
__device__ void scan_full_aos(const float4* __restrict__ P4, KSmem& sm,
                              float qx, float qy, float qz,
                              int tid, int lane, int wid, bool save_tau) {
    for (int j = tid; j < BINS; j += TPB) sm.hist[j] = 0u;
    if (tid == 0) { sm.ns = 0; sm.T = 0u; }
    __syncthreads();
    for (int grp = tid; grp < SAMPLE_GRPS; grp += TPB) {
        float4 f0 = P4[3 * grp + 0];
        float4 f1 = P4[3 * grp + 1];
        float4 f2 = P4[3 * grp + 2];
        atomicAdd(&sm.hist[__float_as_uint(dist2f(f0.x, f0.y, f0.z, qx, qy, qz)) >> SHIFT], 1u);
        atomicAdd(&sm.hist[__float_as_uint(dist2f(f0.w, f1.x, f1.y, qx, qy, qz)) >> SHIFT], 1u);
        atomicAdd(&sm.hist[__float_as_uint(dist2f(f1.z, f1.w, f2.x, qx, qy, qz)) >> SHIFT], 1u);
        atomicAdd(&sm.hist[__float_as_uint(dist2f(f2.y, f2.z, f2.w, qx, qy, qz)) >> SHIFT], 1u);
    }
    __syncthreads();
    unsigned Tc = find_bin(sm.hist, sm.wsum, &sm.T, RANK_CUT, tid, lane, wid);
    const unsigned tau = (Tc >= BINS - 1) ? 0xFFFFFFFFu : ((Tc + 1) << SHIFT);
    if (save_tau && tid == 0) sm.tau0 = tau;
#pragma unroll 4
    for (int grp = tid; grp < N_PTS / 4; grp += TPB) {
        float4 f0 = P4[3 * grp + 0];
        float4 f1 = P4[3 * grp + 1];
        float4 f2 = P4[3 * grp + 2];
        float xs[4] = {f0.x, f0.w, f1.z, f2.y};
        float ys[4] = {f0.y, f1.x, f1.w, f2.z};
        float zs[4] = {f0.z, f1.y, f2.x, f2.w};
#pragma unroll
        for (int k = 0; k < 4; k++) {
            unsigned uu = __float_as_uint(dist2f(xs[k], ys[k], zs[k], qx, qy, qz));
            if (uu < tau) {
                int p = atomicAdd(&sm.ns, 1);
                if (p < CAP) {
                    sm.u[p] = uu; sm.idx[p] = grp * 4 + k;
                    sm.px[p] = xs[k]; sm.py[p] = ys[k]; sm.pz[p] = zs[k];
                }
            }
        }
    }
    __syncthreads();
}

// Select exact top-G_SIZE from sm.u[0..min(ns,CAP)) -> sm.sel (positions).
// Returns 1 iff selection certainly exact (tie capacity not exceeded).
__device__ int select100(KSmem& sm, int* s_flag, int tid, int lane, int wid) {
    if (tid == 0) { sm.maxu = 0u; sm.nd = 0; sm.nt = 0; sm.T = 0u; *s_flag = 1; }
    __syncthreads();
    int S = sm.ns; if (S > CAP) S = CAP;
    unsigned m = 0;
    for (int i = tid; i < S; i += TPB) m = max(m, sm.u[i]);
#pragma unroll
    for (int off = 32; off > 0; off >>= 1) m = max(m, (unsigned)__shfl_xor((int)m, off));
    if (lane == 0) atomicMax(&sm.maxu, m);
    for (int j = tid; j < BINS; j += TPB) sm.hist[j] = 0u;
    __syncthreads();
    unsigned maxu = sm.maxu;
    unsigned hb = (maxu == 0u) ? 0u : (32u - (unsigned)__clz(maxu));
    unsigned s3 = hb > 12u ? hb - 12u : 0u;
    for (int i = tid; i < S; i += TPB) atomicAdd(&sm.hist[sm.u[i] >> s3], 1u);
    __syncthreads();
    unsigned T2 = find_bin(sm.hist, sm.wsum, &sm.T, G_SIZE, tid, lane, wid);
    const unsigned lo = T2 << s3;
    for (int i = tid; i < S; i += TPB) {
        unsigned uu = sm.u[i];
        if (uu < lo) {
            int p = atomicAdd(&sm.nd, 1);
            if (p < G_SIZE) sm.sel[p] = i;
        } else if ((uu >> s3) == T2) {
            int p = atomicAdd(&sm.nt, 1);
            if (p < TIE_CAP) { sm.tu[p] = uu; sm.ti[p] = i; }
        }
    }
    __syncthreads();
    if (tid == 0) {
        int bad = 0;
        int nd = sm.nd; if (nd > G_SIZE) nd = G_SIZE;
        int need = G_SIZE - nd;
        if (sm.nt > TIE_CAP) bad = 1;
        int ec = sm.nt; if (ec > TIE_CAP) ec = TIE_CAP;
        if (need > ec) bad = 1;
        for (int a = 0; a < need && a < ec; ++a) {
            int best = a;
            for (int j = a + 1; j < ec; ++j)
                if (sm.tu[j] < sm.tu[best] ||
                    (sm.tu[j] == sm.tu[best] && sm.idx[sm.ti[j]] < sm.idx[sm.ti[best]])) best = j;
            unsigned tub = sm.tu[best]; sm.tu[best] = sm.tu[a]; sm.tu[a] = tub;
            int tib = sm.ti[best]; sm.ti[best] = sm.ti[a]; sm.ti[a] = tib;
            sm.sel[nd + a] = sm.ti[a];
        }
        *s_flag = !bad;
    }
    __syncthreads();
    return *s_flag;
}

// ---- 3x3 symmetric eigensolve (Jacobi, double) ----
__device__ void eig3(const float cf[6], double lam_out[3], double dir_out[3]) {
    double a[3][3], v[3][3];
    a[0][0] = cf[0]; a[0][1] = cf[1]; a[0][2] = cf[2];
    a[1][0] = cf[1]; a[1][1] = cf[3]; a[1][2] = cf[4];
    a[2][0] = cf[2]; a[2][1] = cf[4]; a[2][2] = cf[5];
    for (int i = 0; i < 3; i++)
        for (int j = 0; j < 3; j++) v[i][j] = (i == j) ? 1.0 : 0.0;
    for (int sweep = 0; sweep < 12; sweep++) {
        double off = a[0][1] * a[0][1] + a[0][2] * a[0][2] + a[1][2] * a[1][2];
        if (off == 0.0) break;
        for (int p = 0; p < 2; p++) {
            for (int q = p + 1; q < 3; q++) {
                double apq = a[p][q];
                if (apq == 0.0) continue;
                double app = a[p][p], aqq = a[q][q];
                double theta = (aqq - app) / (2.0 * apq);
                double t = (theta >= 0.0 ? 1.0 : -1.0) /
                           (fabs(theta) + sqrt(theta * theta + 1.0));
                double c = 1.0 / sqrt(t * t + 1.0);
                double s = t * c;
                a[p][p] = app - t * apq;
                a[q][q] = aqq + t * apq;
                a[p][q] = 0.0; a[q][p] = 0.0;
                for (int r = 0; r < 3; r++) {
                    if (r == p || r == q) continue;
                    double arp = a[r][p], arq = a[r][q];
                    a[r][p] = c * arp - s * arq; a[p][r] = a[r][p];
                    a[r][q] = s * arp + c * arq; a[q][r] = a[r][q];
                }
                for (int r = 0; r < 3; r++) {
                    double vrp = v[r][p], vrq = v[r][q];
                    v[r][p] = c * vrp - s * vrq;
                    v[r][q] = s * vrp + c * vrq;
                }
            }
        }
    }
    double l0 = a[0][0], l1 = a[1][1], l2 = a[2][2];
    int i0 = 0, i1 = 1, i2 = 2;
    if (l0 > l1) { double t = l0; l0 = l1; l1 = t; int ti = i0; i0 = i1; i1 = ti; }
    if (l1 > l2) { double t = l1; l1 = l2; l2 = t; int ti = i1; i1 = i2; i2 = ti; }
    if (l0 > l1) { double t = l0; l0 = l1; l1 = t; int ti = i0; i0 = i1; i1 = ti; }
    lam_out[0] = l0; lam_out[1] = l1; lam_out[2] = l2;
    dir_out[0] = v[0][i2]; dir_out[1] = v[1][i2]; dir_out[2] = v[2][i2];
}

// One block per (batch, group). Slab path: load survivors, select, mean,
// certified phase-1 re-rank; fallback anywhere -> full AoS scan. Then cov,
// release-only election, last block finalizes inline.
__global__ __launch_bounds__(TPB)
void merge_kernel(const float* __restrict__ pts,
                  const unsigned* __restrict__ taus,
                  const unsigned* __restrict__ cnts,
                  const uint2* __restrict__ slabs,
                  float* __restrict__ gmeans, float* __restrict__ covs,
                  float* __restrict__ out,
                  unsigned* __restrict__ syncw,
                  int B, int nblk, int use_slabs) {
    __shared__ KSmem sm;
    __shared__ int s_flag, s_ok, s_last, s_fb;
    __shared__ unsigned s_cnt[NCHUNK];
    __shared__ int s_pre[NCHUNK];

    const int blk = blockIdx.x;
    const int b = blk % B;
    const int g = blk / B;
    const int gi = b * G_NUMS + g;
    const float* __restrict__ P = pts + (size_t)b * (N_PTS * 3);
    const float4* __restrict__ P4 = (const float4*)P;
    const int tid = threadIdx.x;
    const int lane = tid & 63, wid = tid >> 6;

    if (tid == 0) {
        const float* qp = P + (size_t)g * PT_STRIDE * 3;
        sm.q[0] = qp[0]; sm.q[1] = qp[1]; sm.q[2] = qp[2];
        s_fb = !use_slabs;
        s_last = 0;
    }
    if (tid < 3) sm.acc[tid] = 0.f;
    if (tid < 6) sm.cov[tid] = 0.f;
    __syncthreads();
    const float qx = sm.q[0], qy = sm.q[1], qz = sm.q[2];

    // ---- phase 0: survivors from slabs (or full scan fallback) ----
    if (!s_fb) {
        if (tid < NCHUNK) s_cnt[tid] = cnts[(size_t)gi * NCHUNK + tid];
        __syncthreads();
        if (tid == 0) {
            int tot = 0, bad = 0;
            for (int cc = 0; cc < NCHUNK; ++cc) {
                unsigned n = s_cnt[cc];
                if (n > SLAB_CAP) bad = 1;
                s_pre[cc] = tot;
                tot += (int)(n > SLAB_CAP ? SLAB_CAP : n);
            }
            if (tot < G_SIZE || tot > CAP) bad = 1;
            sm.ns = tot;
            sm.tau0 = taus[gi];
            s_fb = bad;
        }
        __syncthreads();
        if (!s_fb) {
            const uint2* sl = slabs + (size_t)gi * NCHUNK * SLAB_CAP;
            for (int e = tid; e < NCHUNK * SLAB_CAP; e += TPB) {
                int cc = e / SLAB_CAP, p = e % SLAB_CAP;
                unsigned n = s_cnt[cc]; if (n > SLAB_CAP) n = SLAB_CAP;
                if ((unsigned)p < n) {
                    uint2 s = sl[e];
                    int pos = s_pre[cc] + p;
                    sm.u[pos] = s.x; sm.idx[pos] = (int)s.y;
                }
            }
            __syncthreads();
            int S = sm.ns;
            for (int i = tid; i < S; i += TPB) {
                const float* pp = P + 3 * (size_t)sm.idx[i];
                sm.px[i] = pp[0]; sm.py[i] = pp[1]; sm.pz[i] = pp[2];
            }
            __syncthreads();
            if (!select100(sm, &s_flag, tid, lane, wid)) {
                if (tid == 0) s_fb = 1;
                __syncthreads();
            }
        }
    }
    if (s_fb) {
        scan_full_aos(P4, sm, qx, qy, qz, tid, lane, wid, true);
        select100(sm, &s_flag, tid, lane, wid);
    }

    // ---- mean -> q1 ----
    if (tid < G_SIZE) {
        int p = sm.sel[tid];
        atomicAdd(&sm.acc[0], sm.px[p]);
        atomicAdd(&sm.acc[1], sm.py[p]);
        atomicAdd(&sm.acc[2], sm.pz[p]);
    }
    __syncthreads();
    if (tid == 0) {
        float mx = sm.acc[0] * (1.0f / G_SIZE);
        float my = sm.acc[1] * (1.0f / G_SIZE);
        float mz = sm.acc[2] * (1.0f / G_SIZE);
        gmeans[(size_t)gi * 3 + 0] = mx;
        gmeans[(size_t)gi * 3 + 1] = my;
        gmeans[(size_t)gi * 3 + 2] = mz;
        float dx = mx - qx, dy = my - qy, dz = mz - qz;
        sm.delta2 = fmaf(dx, dx, fmaf(dy, dy, dz * dz));
        sm.q[0] = mx; sm.q[1] = my; sm.q[2] = mz;
        sm.acc[0] = 0.f; sm.acc[1] = 0.f; sm.acc[2] = 0.f;
        sm.r1 = 0u;
    }
    __syncthreads();
    const float q1x = sm.q[0], q1y = sm.q[1], q1z = sm.q[2];

    // ---- phase 1: certified survivor re-rank ----
    {
        int S = sm.ns; if (S > CAP) S = CAP;
        for (int i = tid; i < S; i += TPB)
            sm.u[i] = __float_as_uint(dist2f(sm.px[i], sm.py[i], sm.pz[i], q1x, q1y, q1z));
        int ok1 = select100(sm, &s_flag, tid, lane, wid);
        if (tid < G_SIZE) atomicMax(&sm.r1, sm.u[sm.sel[tid]]);
        __syncthreads();
        if (tid == 0) {
            int ok = ok1;
            // certificate: every non-survivor p has d0(p) >= R0, so
            // d1(p) >= R0 - delta; exact iff R0 - delta > r1 (fp margin)
            double R0 = sqrt((double)__uint_as_float(sm.tau0));
            double dl = sqrt((double)sm.delta2);
            double r1 = sqrt((double)__uint_as_float(sm.r1));
            if (!((R0 - dl) > r1 * 1.0001 + 1e-7)) ok = 0;
            s_ok = ok;
        }
        __syncthreads();
        if (!s_ok) {
            scan_full_aos(P4, sm, q1x, q1y, q1z, tid, lane, wid, false);
            select100(sm, &s_flag, tid, lane, wid);
        }
    }

    // ---- mean / covariance over the exact 100 ----
    float px = 0.f, py = 0.f, pz = 0.f;
    if (tid < G_SIZE) {
        int p = sm.sel[tid];
        px = sm.px[p]; py = sm.py[p]; pz = sm.pz[p];
        atomicAdd(&sm.acc[0], px);
        atomicAdd(&sm.acc[1], py);
        atomicAdd(&sm.acc[2], pz);
    }
    __syncthreads();
    float mx = sm.acc[0] * (1.0f / G_SIZE);
    float my = sm.acc[1] * (1.0f / G_SIZE);
    float mz = sm.acc[2] * (1.0f / G_SIZE);
    if (tid < G_SIZE) {
        float x = px - mx, y = py - my, z = pz - mz;
        atomicAdd(&sm.cov[0], x * x);
        atomicAdd(&sm.cov[1], x * y);
        atomicAdd(&sm.cov[2], x * z);
        atomicAdd(&sm.cov[3], y * y);
        atomicAdd(&sm.cov[4], y * z);
        atomicAdd(&sm.cov[5], z * z);
    }
    __syncthreads();
    if (tid < 6) covs[(size_t)gi * 6 + tid] = sm.cov[tid] * (1.0f / G_SIZE);

    // ---- last-block election (release-only; after ALL heavy work) ----
    __syncthreads();
    if (tid == 0) {
        unsigned old = __hip_atomic_fetch_add(&syncw[0], 1u, __ATOMIC_RELEASE,
                                              __HIP_MEMORY_SCOPE_AGENT);
        s_last = (old == (unsigned)(nblk - 1)) ? 1 : 0;
    }
    __syncthreads();
    if (!s_last) return;

    // ---- finalize (runs once, in the last block) ----
    (void)__hip_atomic_load(&syncw[0], __ATOMIC_ACQUIRE, __HIP_MEMORY_SCOPE_AGENT);
    const int NG = nblk;
    float et = 0.f;
    if (tid < NG) {
        float cf[6];
#pragma unroll
        for (int j = 0; j < 6; j++) cf[j] = covs[tid * 6 + j];
        double lam[3], dir[3];
        eig3(cf, lam, dir);
        double denom = lam[0] + lam[1] + lam[2] + 1e-9;
        et = (float)((lam[2] - lam[1]) / denom);
        sm.fin.dir[tid][0] = (float)dir[0];
        sm.fin.dir[tid][1] = (float)dir[1];
        sm.fin.dir[tid][2] = (float)dir[2];
        sm.fin.gm[tid][0] = gmeans[tid * 3 + 0];
        sm.fin.gm[tid][1] = gmeans[tid * 3 + 1];
        sm.fin.gm[tid][2] = gmeans[tid * 3 + 2];
    }
    __syncthreads();

    float st = 0.f;
    if (tid < NG) {
        int bb = tid / G_NUMS, gg0 = tid % G_NUMS;
        float gx = sm.fin.gm[tid][0], gy = sm.fin.gm[tid][1], gz = sm.fin.gm[tid][2];
        float bd = 3.4e38f; int bj = 0;
        for (int gg = 0; gg < G_NUMS; gg++) {
            if (gg == gg0) continue;
            int o = bb * G_NUMS + gg;
            float dx = gx - sm.fin.gm[o][0];
            float dy = gy - sm.fin.gm[o][1];
            float dz = gz - sm.fin.gm[o][2];
            float d = dx * dx + dy * dy + dz * dz;
            if (d < bd) { bd = d; bj = gg; }
        }
        int o = bb * G_NUMS + bj;
        float cosv = sm.fin.dir[tid][0] * sm.fin.dir[o][0] +
                     sm.fin.dir[tid][1] * sm.fin.dir[o][1] +
                     sm.fin.dir[tid][2] * sm.fin.dir[o][2];
        st = 1.f - cosv * cosv;
    }

    float e = et, s2 = st;
#pragma unroll
    for (int off = 32; off > 0; off >>= 1) {
        e += __shfl_down(e, off);
        s2 += __shfl_down(s2, off);
    }
    if (lane == 0) { sm.fin.pe[wid] = e; sm.fin.ps[wid] = s2; }
    __syncthreads();
    if (tid == 0) {
        float se = 0.f, ss = 0.f;
        for (int w = 0; w < NWAVES; w++) { se += sm.fin.pe[w]; ss += sm.fin.ps[w]; }
        out[0] = -se / (float)B + ss / (float)NG;
    }
}

extern "C" void kernel_launch(void* const* d_in, const int* in_sizes, int n_in,
                              void* d_out, int out_size, void* d_ws, size_t ws_size,
                              hipStream_t stream) {
    const float* pts = (const float*)d_in[0];
    float* out = (float*)d_out;
    float* ws = (float*)d_ws;
    int B = in_sizes[0] / (N_PTS * 3);   // 8
    int nblk = B * G_NUMS;               // 240

    float* gmeans = ws;                                  // 3*nblk floats
    float* covs = ws + (size_t)3 * nblk;                 // 6*nblk floats
    unsigned* syncw = (unsigned*)(ws + (size_t)9 * nblk);          // 16 u32
    unsigned* taus = syncw + 16;                                   // nblk u32
    unsigned* cnts = taus + nblk;                                  // nblk*NCHUNK u32
    size_t slab_off_u32 = (size_t)9 * nblk + 16 + nblk + (size_t)nblk * NCHUNK;
    slab_off_u32 = (slab_off_u32 + 1) & ~(size_t)1;                // 8-byte align
    uint2* slabs = (uint2*)((unsigned*)ws + slab_off_u32);
    size_t need = (slab_off_u32 + (size_t)nblk * NCHUNK * SLAB_CAP * 2) * 4;
    const int use_slabs = ws_size >= need;

    if (use_slabs) {
        scan_kernel<<<dim3(B * NCHUNK), dim3(TPB), 0, stream>>>(
            pts, taus, cnts, slabs, syncw, B);
    } else {
        hipMemsetAsync(syncw, 0, 64, stream);
    }
    merge_kernel<<<dim3(nblk), dim3(TPB), 0, stream>>>(
        pts, taus, cnts, slabs, gmeans, covs, out, syncw, B, nblk, use_slabs);
}

// Round 7
// 175.736 us; speedup vs baseline: 1.0382x; 1.0382x over previous
//
#include <hip/hip_runtime.h>
#include <math.h>

#define N_PTS     131072
#define G_NUMS    30
#define G_SIZE    100
#define PT_STRIDE (N_PTS / G_NUMS)   // 4369
#define TPB       512
#define NWAVES    (TPB / 64)         // 8
#define BINS      4096
#define JB        (BINS / TPB)       // 8 bins per thread
#define SHIFT     20

// chunk-parallel scan
#define NCHUNK    32
#define CHUNK     (N_PTS / NCHUNK)   // 4096 points per chunk
#define CPT       (CHUNK / TPB)      // 8 points per thread
#define SMP_N     2048               // scan-kernel sample (iid: first 2048 pts)
#define SMP_PL    (SMP_N / 64)       // 32 sample points per lane
#define SMP_CUT   16                 // 16th of 2048 ~ quantile 1/128
#define SMP_ITERS 14                 // bisection depth (<=0.01% tau looseness)
#define SLAB_CAP  128                // per-(group,chunk) survivor slab

// merge / fallback path
#define SAMPLE_GRPS 1024             // fallback sample: first 4096 pts (AoS)
#define RANK_CUT  32
#define CAP       3072               // max merged survivors held in LDS
#define TIE_CAP   64

__device__ __forceinline__ float dist2f(float px, float py, float pz,
                                        float qx, float qy, float qz) {
    float dx = px - qx, dy = py - qy, dz = pz - qz;
    return fmaf(dx, dx, fmaf(dy, dy, dz * dz));
}

// Find smallest bin T such that cumulative count through T >= rank.
// hist[BINS] populated; wsum[NWAVES], *T shared scratch. 3 internal barriers.
__device__ __forceinline__ unsigned find_bin(unsigned* hist, unsigned* wsum,
                                             unsigned* T, unsigned rank,
                                             int tid, int lane, int wid) {
    unsigned hv[JB], csum = 0;
#pragma unroll
    for (int j = 0; j < JB; j++) { hv[j] = hist[tid * JB + j]; csum += hv[j]; }
    unsigned inc = csum;
#pragma unroll
    for (int off = 1; off < 64; off <<= 1) {
        unsigned n = __shfl_up(inc, off);
        if (lane >= off) inc += n;
    }
    __syncthreads();                  // protect wsum reuse across calls
    if (lane == 63) wsum[wid] = inc;
    __syncthreads();
    unsigned base = 0;
    for (int w = 0; w < wid; w++) base += wsum[w];
    unsigned c = base + inc - csum;   // exclusive prefix before this thread's chunk
#pragma unroll
    for (int j = 0; j < JB; j++) {
        if (c < rank && c + hv[j] >= rank) *T = (unsigned)(tid * JB + j);
        c += hv[j];
    }
    __syncthreads();
    return *T;
}

// =============================== scan kernel ===============================
// One block per (batch, chunk). Reads each point ONCE.
// tau per query via wave-parallel register bisection on a 2048-pt sample
// (deterministic: identical inputs + op order across all chunk-blocks).
__global__ __launch_bounds__(TPB)
void scan_kernel(const float* __restrict__ pts,
                 unsigned* __restrict__ taus, unsigned* __restrict__ cnts,
                 float4* __restrict__ slabF, unsigned* __restrict__ slabI,
                 unsigned* __restrict__ syncw, int B) {
    __shared__ float s_buf[CHUNK * 3];      // 48 KB: sample, then own chunk
    __shared__ float qb[G_NUMS * 3];
    __shared__ unsigned s_tau[G_NUMS];
    __shared__ unsigned s_cnt[G_NUMS];

    const int b = blockIdx.x % B;           // batch-per-XCD swizzle (L2 locality)
    const int c = blockIdx.x / B;
    const float* __restrict__ P = pts + (size_t)b * (N_PTS * 3);
    const float4* __restrict__ P4 = (const float4*)P;
    const int tid = threadIdx.x;
    const int lane = tid & 63, wid = tid >> 6;

    if (blockIdx.x == 0 && tid == 0) syncw[0] = 0;   // replaces memset dispatch

    if (tid < G_NUMS) {
        const float* qp = P + (size_t)tid * PT_STRIDE * 3;
        qb[tid * 3 + 0] = qp[0]; qb[tid * 3 + 1] = qp[1]; qb[tid * 3 + 2] = qp[2];
        s_cnt[tid] = 0u;
    }
    // ---- stage sample (coalesced float4) ----
    for (int j = tid; j < SMP_N * 3 / 4; j += TPB) ((float4*)s_buf)[j] = P4[j];
    __syncthreads();

    // ---- wave-parallel tau bisection: wave w owns queries 4w..4w+3 ----
    {
        int g0 = wid * 4;
        for (int g = g0; g < g0 + 4 && g < G_NUMS; ++g) {
            float qx = qb[g * 3 + 0], qy = qb[g * 3 + 1], qz = qb[g * 3 + 2];
            unsigned du[SMP_PL];
#pragma unroll
            for (int k = 0; k < SMP_PL; ++k) {
                int p = lane + 64 * k;      // stride-3 LDS: conflict-free
                du[k] = __float_as_uint(
                    dist2f(s_buf[3 * p], s_buf[3 * p + 1], s_buf[3 * p + 2],
                           qx, qy, qz));
            }
            unsigned lo = 0u, hi = 0x7F800000u;   // count(<lo)<CUT<=count(<hi)
            for (int it = 0; it < SMP_ITERS; ++it) {
                unsigned mid = (lo + hi) >> 1;
                int cnt = 0;
#pragma unroll
                for (int k = 0; k < SMP_PL; ++k) cnt += (du[k] < mid) ? 1 : 0;
#pragma unroll
                for (int off = 1; off < 64; off <<= 1) cnt += __shfl_xor(cnt, off);
                if (cnt >= SMP_CUT) hi = mid; else lo = mid;   // uniform branch
            }
            if (lane == 0) s_tau[g] = hi;   // upper bracket: tau >= exact stat
        }
    }
    __syncthreads();                        // taus ready; s_buf reusable

    // ---- stage own chunk -> regs ----
    const float4* C4 = P4 + (size_t)c * (CHUNK * 3 / 4);
    for (int j = tid; j < CHUNK * 3 / 4; j += TPB) ((float4*)s_buf)[j] = C4[j];
    __syncthreads();
    float cp[CPT][3];
#pragma unroll
    for (int k = 0; k < CPT; ++k) {
        int p = tid + k * TPB;
        cp[k][0] = s_buf[3 * p + 0];
        cp[k][1] = s_buf[3 * p + 1];
        cp[k][2] = s_buf[3 * p + 2];
    }
    // (no barrier: s_buf not written again)

    // ---- filter chunk for all 30 queries; rare hits -> global slabs ----
    const int ibase = c * CHUNK + tid;
    for (int g = 0; g < G_NUMS; ++g) {
        float qx = qb[g * 3 + 0], qy = qb[g * 3 + 1], qz = qb[g * 3 + 2];
        unsigned tau = s_tau[g];
        float4* slF = slabF + ((size_t)(b * G_NUMS + g) * NCHUNK + c) * SLAB_CAP;
        unsigned* slI = slabI + ((size_t)(b * G_NUMS + g) * NCHUNK + c) * SLAB_CAP;
#pragma unroll
        for (int k = 0; k < CPT; ++k) {
            float d2 = dist2f(cp[k][0], cp[k][1], cp[k][2], qx, qy, qz);
            if (__float_as_uint(d2) < tau) {
                unsigned p = atomicAdd(&s_cnt[g], 1u);
                if (p < SLAB_CAP) {
                    slF[p] = make_float4(d2, cp[k][0], cp[k][1], cp[k][2]);
                    slI[p] = (unsigned)(ibase + k * TPB);
                }
            }
        }
    }
    __syncthreads();
    if (tid < G_NUMS)
        cnts[(size_t)(b * G_NUMS + tid) * NCHUNK + c] = s_cnt[tid];  // RAW
    if (c == 0 && tid < G_NUMS)
        taus[b * G_NUMS + tid] = s_tau[tid];
}

// =============================== merge kernel ==============================
struct KSmem {
    union {
        unsigned hist[BINS];         // 16 KB
        struct {                     // finalize overlay (last block only)
            float gm[256][3];
            float dir[256][3];
            float pe[NWAVES];
            float ps[NWAVES];
        } fin;
    };
    unsigned wsum[NWAVES];
    unsigned T;
    int ns, nd, nt;
    unsigned u[CAP];
    int idx[CAP];
    float px[CAP], py[CAP], pz[CAP];
    int sel[G_SIZE];                 // positions into survivor arrays
    unsigned tu[TIE_CAP];
    int ti[TIE_CAP];                 // positions
    float acc[3], cov[6], q[3];
    unsigned tau0, maxu, r1;
    float delta2;
};

// AoS full scan (fallback): fills sm.u/idx/px/py/pz/ns (and tau0 if save_tau).
__device__ void scan_full_aos(const float4* __restrict__ P4, KSmem& sm,
                              float qx, float qy, float qz,
                              int tid, int lane, int wid, bool save_tau) {
    for (int j = tid; j < BINS; j += TPB) sm.hist[j] = 0u;
    if (tid == 0) { sm.ns = 0; sm.T = 0u; }
    __syncthreads();
    for (int grp = tid; grp < SAMPLE_GRPS; grp += TPB) {
        float4 f0 = P4[3 * grp + 0];
        float4 f1 = P4[3 * grp + 1];
        float4 f2 = P4[3 * grp + 2];
        atomicAdd(&sm.hist[__float_as_uint(dist2f(f0.x, f0.y, f0.z, qx, qy, qz)) >> SHIFT], 1u);
        atomicAdd(&sm.hist[__float_as_uint(dist2f(f0.w, f1.x, f1.y, qx, qy, qz)) >> SHIFT], 1u);
        atomicAdd(&sm.hist[__float_as_uint(dist2f(f1.z, f1.w, f2.x, qx, qy, qz)) >> SHIFT], 1u);
        atomicAdd(&sm.hist[__float_as_uint(dist2f(f2.y, f2.z, f2.w, qx, qy, qz)) >> SHIFT], 1u);
    }
    __syncthreads();
    unsigned Tc = find_bin(sm.hist, sm.wsum, &sm.T, RANK_CUT, tid, lane, wid);
    const unsigned tau = (Tc >= BINS - 1) ? 0xFFFFFFFFu : ((Tc + 1) << SHIFT);
    if (save_tau && tid == 0) sm.tau0 = tau;
#pragma unroll 4
    for (int grp = tid; grp < N_PTS / 4; grp += TPB) {
        float4 f0 = P4[3 * grp + 0];
        float4 f1 = P4[3 * grp + 1];
        float4 f2 = P4[3 * grp + 2];
        float xs[4] = {f0.x, f0.w, f1.z, f2.y};
        float ys[4] = {f0.y, f1.x, f1.w, f2.z};
        float zs[4] = {f0.z, f1.y, f2.x, f2.w};
#pragma unroll
        for (int k = 0; k < 4; k++) {
            unsigned uu = __float_as_uint(dist2f(xs[k], ys[k], zs[k], qx, qy, qz));
            if (uu < tau) {
                int p = atomicAdd(&sm.ns, 1);
                if (p < CAP) {
                    sm.u[p] = uu; sm.idx[p] = grp * 4 + k;
                    sm.px[p] = xs[k]; sm.py[p] = ys[k]; sm.pz[p] = zs[k];
                }
            }
        }
    }
    __syncthreads();
}

// Select exact top-G_SIZE from sm.u[0..min(ns,CAP)) -> sm.sel (positions).
// Returns 1 iff selection certainly exact (tie capacity not exceeded).
__device__ int select100(KSmem& sm, int* s_flag, int tid, int lane, int wid) {
    if (tid == 0) { sm.maxu = 0u; sm.nd = 0; sm.nt = 0; sm.T = 0u; *s_flag = 1; }
    __syncthreads();
    int S = sm.ns; if (S > CAP) S = CAP;
    unsigned m = 0;
    for (int i = tid; i < S; i += TPB) m = max(m, sm.u[i]);
#pragma unroll
    for (int off = 32; off > 0; off >>= 1) m = max(m, (unsigned)__shfl_xor((int)m, off));
    if (lane == 0) atomicMax(&sm.maxu, m);
    for (int j = tid; j < BINS; j += TPB) sm.hist[j] = 0u;
    __syncthreads();
    unsigned maxu = sm.maxu;
    unsigned hb = (maxu == 0u) ? 0u : (32u - (unsigned)__clz(maxu));
    unsigned s3 = hb > 12u ? hb - 12u : 0u;
    for (int i = tid; i < S; i += TPB) atomicAdd(&sm.hist[sm.u[i] >> s3], 1u);
    __syncthreads();
    unsigned T2 = find_bin(sm.hist, sm.wsum, &sm.T, G_SIZE, tid, lane, wid);
    const unsigned lo = T2 << s3;
    for (int i = tid; i < S; i += TPB) {
        unsigned uu = sm.u[i];
        if (uu < lo) {
            int p = atomicAdd(&sm.nd, 1);
            if (p < G_SIZE) sm.sel[p] = i;
        } else if ((uu >> s3) == T2) {
            int p = atomicAdd(&sm.nt, 1);
            if (p < TIE_CAP) { sm.tu[p] = uu; sm.ti[p] = i; }
        }
    }
    __syncthreads();
    if (tid == 0) {
        int bad = 0;
        int nd = sm.nd; if (nd > G_SIZE) nd = G_SIZE;
        int need = G_SIZE - nd;
        if (sm.nt > TIE_CAP) bad = 1;
        int ec = sm.nt; if (ec > TIE_CAP) ec = TIE_CAP;
        if (need > ec) bad = 1;
        for (int a = 0; a < need && a < ec; ++a) {
            int best = a;
            for (int j = a + 1; j < ec; ++j)
                if (sm.tu[j] < sm.tu[best] ||
                    (sm.tu[j] == sm.tu[best] && sm.idx[sm.ti[j]] < sm.idx[sm.ti[best]])) best = j;
            unsigned tub = sm.tu[best]; sm.tu[best] = sm.tu[a]; sm.tu[a] = tub;
            int tib = sm.ti[best]; sm.ti[best] = sm.ti[a]; sm.ti[a] = tib;
            sm.sel[nd + a] = sm.ti[a];
        }
        *s_flag = !bad;
    }
    __syncthreads();
    return *s_flag;
}

// ---- 3x3 symmetric eigensolve (Jacobi, double) ----
__device__ void eig3(const float cf[6], double lam_out[3], double dir_out[3]) {
    double a[3][3], v[3][3];
    a[0][0] = cf[0]; a[0][1] = cf[1]; a[0][2] = cf[2];
    a[1][0] = cf[1]; a[1][1] = cf[3]; a[1][2] = cf[4];
    a[2][0] = cf[2]; a[2][1] = cf[4]; a[2][2] = cf[5];
    for (int i = 0; i < 3; i++)
        for (int j = 0; j < 3; j++) v[i][j] = (i == j) ? 1.0 : 0.0;
    for (int sweep = 0; sweep < 12; sweep++) {
        double off = a[0][1] * a[0][1] + a[0][2] * a[0][2] + a[1][2] * a[1][2];
        if (off == 0.0) break;
        for (int p = 0; p < 2; p++) {
            for (int q = p + 1; q < 3; q++) {
                double apq = a[p][q];
                if (apq == 0.0) continue;
                double app = a[p][p], aqq = a[q][q];
                double theta = (aqq - app) / (2.0 * apq);
                double t = (theta >= 0.0 ? 1.0 : -1.0) /
                           (fabs(theta) + sqrt(theta * theta + 1.0));
                double c = 1.0 / sqrt(t * t + 1.0);
                double s = t * c;
                a[p][p] = app - t * apq;
                a[q][q] = aqq + t * apq;
                a[p][q] = 0.0; a[q][p] = 0.0;
                for (int r = 0; r < 3; r++) {
                    if (r == p || r == q) continue;
                    double arp = a[r][p], arq = a[r][q];
                    a[r][p] = c * arp - s * arq; a[p][r] = a[r][p];
                    a[r][q] = s * arp + c * arq; a[q][r] = a[r][q];
                }
                for (int r = 0; r < 3; r++) {
                    double vrp = v[r][p], vrq = v[r][q];
                    v[r][p] = c * vrp - s * vrq;
                    v[r][q] = s * vrp + c * vrq;
                }
            }
        }
    }
    double l0 = a[0][0], l1 = a[1][1], l2 = a[2][2];
    int i0 = 0, i1 = 1, i2 = 2;
    if (l0 > l1) { double t = l0; l0 = l1; l1 = t; int ti = i0; i0 = i1; i1 = ti; }
    if (l1 > l2) { double t = l1; l1 = l2; l2 = t; int ti = i1; i1 = i2; i2 = ti; }
    if (l0 > l1) { double t = l0; l0 = l1; l1 = t; int ti = i0; i0 = i1; i1 = ti; }
    lam_out[0] = l0; lam_out[1] = l1; lam_out[2] = l2;
    dir_out[0] = v[0][i2]; dir_out[1] = v[1][i2]; dir_out[2] = v[2][i2];
}

// One block per (batch, group). Slab path: survivors (with coords) from slabs,
// select, mean, certified phase-1 re-rank; any failure -> full AoS scan.
// Then cov, release-only election, last block finalizes inline.
__global__ __launch_bounds__(TPB)
void merge_kernel(const float* __restrict__ pts,
                  const unsigned* __restrict__ taus,
                  const unsigned* __restrict__ cnts,
                  const float4* __restrict__ slabF,
                  const unsigned* __restrict__ slabI,
                  float* __restrict__ gmeans, float* __restrict__ covs,
                  float* __restrict__ out,
                  unsigned* __restrict__ syncw,
                  int B, int nblk, int use_slabs) {
    __shared__ KSmem sm;
    __shared__ int s_flag, s_ok, s_last, s_fb;
    __shared__ unsigned s_cnt[NCHUNK];
    __shared__ int s_pre[NCHUNK];

    const int blk = blockIdx.x;
    const int b = blk % B;
    const int g = blk / B;
    const int gi = b * G_NUMS + g;
    const float* __restrict__ P = pts + (size_t)b * (N_PTS * 3);
    const float4* __restrict__ P4 = (const float4*)P;
    const int tid = threadIdx.x;
    const int lane = tid & 63, wid = tid >> 6;

    if (tid == 0) {
        const float* qp = P + (size_t)g * PT_STRIDE * 3;
        sm.q[0] = qp[0]; sm.q[1] = qp[1]; sm.q[2] = qp[2];
        s_fb = !use_slabs;
        s_last = 0;
    }
    if (tid < 3) sm.acc[tid] = 0.f;
    if (tid < 6) sm.cov[tid] = 0.f;
    __syncthreads();
    const float qx = sm.q[0], qy = sm.q[1], qz = sm.q[2];

    // ---- phase 0: survivors from slabs (or full scan fallback) ----
    if (!s_fb) {
        if (tid < NCHUNK) s_cnt[tid] = cnts[(size_t)gi * NCHUNK + tid];
        __syncthreads();
        if (tid == 0) {
            int tot = 0, bad = 0;
            for (int cc = 0; cc < NCHUNK; ++cc) {
                unsigned n = s_cnt[cc];
                if (n > SLAB_CAP) bad = 1;
                s_pre[cc] = tot;
                tot += (int)(n > SLAB_CAP ? SLAB_CAP : n);
            }
            if (tot < G_SIZE || tot > CAP) bad = 1;
            sm.ns = tot;
            sm.tau0 = taus[gi];
            s_fb = bad;
        }
        __syncthreads();
        if (!s_fb) {
            const float4* slF = slabF + (size_t)gi * NCHUNK * SLAB_CAP;
            const unsigned* slI = slabI + (size_t)gi * NCHUNK * SLAB_CAP;
            for (int e = tid; e < NCHUNK * SLAB_CAP; e += TPB) {
                int cc = e / SLAB_CAP, p = e % SLAB_CAP;
                unsigned n = s_cnt[cc]; if (n > SLAB_CAP) n = SLAB_CAP;
                if ((unsigned)p < n) {
                    float4 f = slF[e];
                    int pos = s_pre[cc] + p;
                    sm.u[pos] = __float_as_uint(f.x);
                    sm.px[pos] = f.y; sm.py[pos] = f.z; sm.pz[pos] = f.w;
                    sm.idx[pos] = (int)slI[e];
                }
            }
            __syncthreads();
            if (!select100(sm, &s_flag, tid, lane, wid)) {
                if (tid == 0) s_fb = 1;
                __syncthreads();
            }
        }
    }
    if (s_fb) {
        scan_full_aos(P4, sm, qx, qy, qz, tid, lane, wid, true);
        select100(sm, &s_flag, tid, lane, wid);
    }

    // ---- mean -> q1 ----
    if (tid < G_SIZE) {
        int p = sm.sel[tid];
        atomicAdd(&sm.acc[0], sm.px[p]);
        atomicAdd(&sm.acc[1], sm.py[p]);
        atomicAdd(&sm.acc[2], sm.pz[p]);
    }
    __syncthreads();
    if (tid == 0) {
        float mx = sm.acc[0] * (1.0f / G_SIZE);
        float my = sm.acc[1] * (1.0f / G_SIZE);
        float mz = sm.acc[2] * (1.0f / G_SIZE);
        gmeans[(size_t)gi * 3 + 0] = mx;
        gmeans[(size_t)gi * 3 + 1] = my;
        gmeans[(size_t)gi * 3 + 2] = mz;
        float dx = mx - qx, dy = my - qy, dz = mz - qz;
        sm.delta2 = fmaf(dx, dx, fmaf(dy, dy, dz * dz));
        sm.q[0] = mx; sm.q[1] = my; sm.q[2] = mz;
        sm.acc[0] = 0.f; sm.acc[1] = 0.f; sm.acc[2] = 0.f;
        sm.r1 = 0u;
    }
    __syncthreads();
    const float q1x = sm.q[0], q1y = sm.q[1], q1z = sm.q[2];

    // ---- phase 1: certified survivor re-rank ----
    {
        int S = sm.ns; if (S > CAP) S = CAP;
        for (int i = tid; i < S; i += TPB)
            sm.u[i] = __float_as_uint(dist2f(sm.px[i], sm.py[i], sm.pz[i], q1x, q1y, q1z));
        int ok1 = select100(sm, &s_flag, tid, lane, wid);
        if (tid < G_SIZE) atomicMax(&sm.r1, sm.u[sm.sel[tid]]);
        __syncthreads();
        if (tid == 0) {
            int ok = ok1;
            // certificate: every non-survivor p has d0(p) >= R0 = sqrt(tau0),
            // so d1(p) >= R0 - delta; exact iff R0 - delta > r1 (fp margin)
            double R0 = sqrt((double)__uint_as_float(sm.tau0));
            double dl = sqrt((double)sm.delta2);
            double r1 = sqrt((double)__uint_as_float(sm.r1));
            if (!((R0 - dl) > r1 * 1.0001 + 1e-7)) ok = 0;
            s_ok = ok;
        }
        __syncthreads();
        if (!s_ok) {
            scan_full_aos(P4, sm, q1x, q1y, q1z, tid, lane, wid, false);
            select100(sm, &s_flag, tid, lane, wid);
        }
    }

    // ---- mean / covariance over the exact 100 ----
    float px = 0.f, py = 0.f, pz = 0.f;
    if (tid < G_SIZE) {
        int p = sm.sel[tid];
        px = sm.px[p]; py = sm.py[p]; pz = sm.pz[p];
        atomicAdd(&sm.acc[0], px);
        atomicAdd(&sm.acc[1], py);
        atomicAdd(&sm.acc[2], pz);
    }
    __syncthreads();
    float mx = sm.acc[0] * (1.0f / G_SIZE);
    float my = sm.acc[1] * (1.0f / G_SIZE);
    float mz = sm.acc[2] * (1.0f / G_SIZE);
    if (tid < G_SIZE) {
        float x = px - mx, y = py - my, z = pz - mz;
        atomicAdd(&sm.cov[0], x * x);
        atomicAdd(&sm.cov[1], x * y);
        atomicAdd(&sm.cov[2], x * z);
        atomicAdd(&sm.cov[3], y * y);
        atomicAdd(&sm.cov[4], y * z);
        atomicAdd(&sm.cov[5], z * z);
    }
    __syncthreads();
    if (tid < 6) covs[(size_t)gi * 6 + tid] = sm.cov[tid] * (1.0f / G_SIZE);

    // ---- last-block election (release-only; after ALL heavy work) ----
    __syncthreads();
    if (tid == 0) {
        unsigned old = __hip_atomic_fetch_add(&syncw[0], 1u, __ATOMIC_RELEASE,
                                              __HIP_MEMORY_SCOPE_AGENT);
        s_last = (old == (unsigned)(nblk - 1)) ? 1 : 0;
    }
    __syncthreads();
    if (!s_last) return;

    // ---- finalize (runs once, in the last block) ----
    (void)__hip_atomic_load(&syncw[0], __ATOMIC_ACQUIRE, __HIP_MEMORY_SCOPE_AGENT);
    const int NG = nblk;
    float et = 0.f;
    if (tid < NG) {
        float cf[6];
#pragma unroll
        for (int j = 0; j < 6; j++) cf[j] = covs[tid * 6 + j];
        double lam[3], dir[3];
        eig3(cf, lam, dir);
        double denom = lam[0] + lam[1] + lam[2] + 1e-9;
        et = (float)((lam[2] - lam[1]) / denom);
        sm.fin.dir[tid][0] = (float)dir[0];
        sm.fin.dir[tid][1] = (float)dir[1];
        sm.fin.dir[tid][2] = (float)dir[2];
        sm.fin.gm[tid][0] = gmeans[tid * 3 + 0];
        sm.fin.gm[tid][1] = gmeans[tid * 3 + 1];
        sm.fin.gm[tid][2] = gmeans[tid * 3 + 2];
    }
    __syncthreads();

    float st = 0.f;
    if (tid < NG) {
        int bb = tid / G_NUMS, gg0 = tid % G_NUMS;
        float gx = sm.fin.gm[tid][0], gy = sm.fin.gm[tid][1], gz = sm.fin.gm[tid][2];
        float bd = 3.4e38f; int bj = 0;
        for (int gg = 0; gg < G_NUMS; gg++) {
            if (gg == gg0) continue;
            int o = bb * G_NUMS + gg;
            float dx = gx - sm.fin.gm[o][0];
            float dy = gy - sm.fin.gm[o][1];
            float dz = gz - sm.fin.gm[o][2];
            float d = dx * dx + dy * dy + dz * dz;
            if (d < bd) { bd = d; bj = gg; }
        }
        int o = bb * G_NUMS + bj;
        float cosv = sm.fin.dir[tid][0] * sm.fin.dir[o][0] +
                     sm.fin.dir[tid][1] * sm.fin.dir[o][1] +
                     sm.fin.dir[tid][2] * sm.fin.dir[o][2];
        st = 1.f - cosv * cosv;
    }

    float e = et, s2 = st;
#pragma unroll
    for (int off = 32; off > 0; off >>= 1) {
        e += __shfl_down(e, off);
        s2 += __shfl_down(s2, off);
    }
    if (lane == 0) { sm.fin.pe[wid] = e; sm.fin.ps[wid] = s2; }
    __syncthreads();
    if (tid == 0) {
        float se = 0.f, ss = 0.f;
        for (int w = 0; w < NWAVES; w++) { se += sm.fin.pe[w]; ss += sm.fin.ps[w]; }
        out[0] = -se / (float)B + ss / (float)NG;
    }
}

extern "C" void kernel_launch(void* const* d_in, const int* in_sizes, int n_in,
                              void* d_out, int out_size, void* d_ws, size_t ws_size,
                              hipStream_t stream) {
    const float* pts = (const float*)d_in[0];
    float* out = (float*)d_out;
    float* ws = (float*)d_ws;
    int B = in_sizes[0] / (N_PTS * 3);   // 8
    int nblk = B * G_NUMS;               // 240

    float* gmeans = ws;                                  // 3*nblk floats
    float* covs = ws + (size_t)3 * nblk;                 // 6*nblk floats
    unsigned* syncw = (unsigned*)(ws + (size_t)9 * nblk);          // 16 u32
    unsigned* taus = syncw + 16;                                   // nblk u32
    unsigned* cnts = taus + nblk;                                  // nblk*NCHUNK u32
    size_t off_u32 = (size_t)9 * nblk + 16 + nblk + (size_t)nblk * NCHUNK;
    off_u32 = (off_u32 + 3) & ~(size_t)3;                          // 16-byte align
    float4* slabF = (float4*)((unsigned*)ws + off_u32);
    size_t slabF_u32 = (size_t)nblk * NCHUNK * SLAB_CAP * 4;
    unsigned* slabI = (unsigned*)ws + off_u32 + slabF_u32;
    size_t need = (off_u32 + slabF_u32 + (size_t)nblk * NCHUNK * SLAB_CAP) * 4;
    const int use_slabs = ws_size >= need;

    if (use_slabs) {
        scan_kernel<<<dim3(B * NCHUNK), dim3(TPB), 0, stream>>>(
            pts, taus, cnts, slabF, slabI, syncw, B);
    } else {
        hipMemsetAsync(syncw, 0, 64, stream);
    }
    merge_kernel<<<dim3(nblk), dim3(TPB), 0, stream>>>(
        pts, taus, cnts, slabF, slabI, gmeans, covs, out, syncw, B, nblk, use_slabs);
}